// Round 7
// baseline (2325.205 us; speedup 1.0000x reference)
//
#include <hip/hip_runtime.h>

// GRU B=64, T=512, IN=128, H=512, L=2, OUT=1 (fp32 in/out).
// R7: XCD-local recurrent exchange.
//   Groups re-mapped so a sync group (layer,m) = {blockIdx === g (mod 8)} -> one
//   XCD under round-robin dispatch. Producers DUAL-STORE h (plain -> local L2
//   dirty/updated-in-place; agent -> MALL, same value). Consumers: plain x4
//   load -> bounded sc0 x4 retries (L2 = within-XCD coherence point) ->
//   unbounded agent/IF u64 loads (placement-independent correctness).
//   Validity = bit0 tag in each packed split-bf16 word (ws poisoned 0xAA,
//   each address written once per launch; cross-replay dirty lines hold
//   identical deterministic values -> benign).
//   grid = 256 x 512 (1 block/CU). layer = (blockIdx&7)>=4; m = blockIdx&3;
//   cb = blockIdx>>3. GEMM: A=[x||h_prev] split-bf16 in LDS; B = register
//   hi/lo bf16 fragments; 3 MFMAs per fp32-accurate product; K split across
//   waves; partials via LDS; 256 epilogue threads do gates + dual store.

constexpr int Bb = 64, Tt = 512, DIN = 128, Hh = 512;
constexpr int BH = Bb * Hh;
constexpr int S0 = 644;    // LDS A-row stride (u32), layer0: 128 x + 512 h + 4 pad
constexpr int S1 = 1028;   // layer1: 512 h0 + 512 h1 + 4 pad
constexpr int PR = 17;     // partials row stride

typedef float  f32x4  __attribute__((ext_vector_type(4)));
typedef short  bf16x8 __attribute__((ext_vector_type(8)));
typedef int    i32x4  __attribute__((ext_vector_type(4)));
typedef unsigned long long u64;

#define MFMA16 __builtin_amdgcn_mfma_f32_16x16x32_bf16

__device__ __forceinline__ unsigned rne_bf16(unsigned xb){
    return (xb + 0x7FFFu + ((xb >> 16) & 1u)) >> 16;
}
__device__ __forceinline__ unsigned pack_split(float x){
    unsigned hb = rne_bf16(__float_as_uint(x));
    float hf = __uint_as_float(hb << 16);
    unsigned lb = rne_bf16(__float_as_uint(x - hf));
    return (hb << 16) | lb;
}
__device__ __forceinline__ float unpack_f32(unsigned u){
    return __uint_as_float(u & 0xFFFF0000u) + __uint_as_float(u << 16);
}

union FragU { unsigned w[4]; bf16x8 v; };

__device__ __forceinline__ void make_wfrag(const float* p, bf16x8& wh, bf16x8& wl){
    FragU hi, lo;
#pragma unroll
    for (int i = 0; i < 4; ++i){
        unsigned pa = pack_split(p[2*i]), pb = pack_split(p[2*i+1]);
        hi.w[i] = (pa >> 16) | (pb & 0xFFFF0000u);
        lo.w[i] = (pa & 0xFFFFu) | (pb << 16);
    }
    wh = hi.v; wl = lo.v;
}
__device__ __forceinline__ void make_afrag(const unsigned* u, bf16x8& ah, bf16x8& al){
    FragU hi, lo;
#pragma unroll
    for (int i = 0; i < 4; ++i){
        unsigned a = u[2*i], b = u[2*i+1];
        hi.w[i] = (a >> 16) | (b & 0xFFFF0000u);
        lo.w[i] = (a & 0xFFFFu) | (b << 16);
    }
    ah = hi.v; al = lo.v;
}

__device__ __forceinline__ u64 ald64(const u64* p){
    return __hip_atomic_load(p, __ATOMIC_RELAXED, __HIP_MEMORY_SCOPE_AGENT);
}
__device__ __forceinline__ void ast32(unsigned* p, unsigned v){
    __hip_atomic_store(p, v, __ATOMIC_RELAXED, __HIP_MEMORY_SCOPE_AGENT);
}

// L1-bypass x4 load: reads the XCD-local L2 line (updated in place by peers'
// plain stores -> within-XCD coherence point).
__device__ __forceinline__ i32x4 ld_sc0(const unsigned* p){
    i32x4 v;
    asm volatile("global_load_dwordx4 %0, %1, off sc0\n\ts_waitcnt vmcnt(0)"
                 : "=v"(v) : "v"(p) : "memory");
    return v;
}
// opaque plain store (kept distinct from the agent store; compiler must not
// fold the pair)
__device__ __forceinline__ void st_plain(unsigned* p, unsigned v){
    asm volatile("global_store_dword %0, %1, off" :: "v"(p), "v"(v) : "memory");
}

// all 4 words must have bit0 == tag
__device__ __forceinline__ bool bad4(const i32x4& v, unsigned tag){
    unsigned x = ((unsigned)v[0] ^ tag) | ((unsigned)v[1] ^ tag)
               | ((unsigned)v[2] ^ tag) | ((unsigned)v[3] ^ tag);
    return (x & 1u) != 0u;
}
// read ladder: (speculative plain already done) -> bounded sc0 -> IF
__device__ __forceinline__ void fix4(const unsigned* p, unsigned tag, i32x4& v){
    if (!bad4(v, tag)) return;
#pragma unroll 1
    for (int i = 0; i < 6; ++i){
        v = ld_sc0(p);
        if (!bad4(v, tag)) return;
        __builtin_amdgcn_s_sleep(1);
    }
    for (;;){
        u64 a = ald64((const u64*)p);
        u64 b = ald64((const u64*)p + 1);
        v[0] = (int)(unsigned)a; v[1] = (int)(unsigned)(a >> 32);
        v[2] = (int)(unsigned)b; v[3] = (int)(unsigned)(b >> 32);
        if (!bad4(v, tag)) return;
        __builtin_amdgcn_s_sleep(2);
    }
}

template<bool BIG>
__global__ __launch_bounds__(512, 1) void gru_main(
    const float* __restrict__ X,
    const float* __restrict__ Wih0, const float* __restrict__ Whh0,
    const float* __restrict__ bih0, const float* __restrict__ bhh0,
    const float* __restrict__ Wih1, const float* __restrict__ Whh1,
    const float* __restrict__ bih1, const float* __restrict__ bhh1,
    const float* __restrict__ fcW, const float* __restrict__ fcb,
    float* __restrict__ out,
    unsigned* hseq0, unsigned* hseq1)
{
    // Kill stale clean L1/L2 lines from the previous graph replay.
    __builtin_amdgcn_fence(__ATOMIC_ACQUIRE, "agent");

    __shared__ unsigned Alds[16 * S1];
    __shared__ float P[8][3][16 * PR];

    const int tid  = threadIdx.x;
    const int lane = tid & 63;
    const int w    = tid >> 6;
    const int g    = (int)blockIdx.x & 7;       // XCD class under round-robin
    const bool isL1 = g >= 4;
    const int m  = g & 3;                        // batch tile 0..3
    const int cb = (int)blockIdx.x >> 3;         // col-block 0..31
    const int c0 = cb * 16;
    const int STR  = isL1 ? S1 : S0;
    const int HOFF = isL1 ? 512 : 128;

    const bool active = isL1 || (w < 5);   // layer0 K=640 -> 5 waves x 128

    // ---- register-resident weight fragments (hi/lo split-bf16) ----
    bf16x8 whi[4][3], wlo[4][3];
    if (active){
        const int n = lane & 15;
#pragma unroll
        for (int ks = 0; ks < 4; ++ks){
            int kq = w * 128 + ks * 32 + (lane >> 4) * 8;
            const float* src; long kloc, rowlen;
            if (isL1){
                if (kq < 512){ src = Wih1; kloc = kq; } else { src = Whh1; kloc = kq - 512; }
                rowlen = 512;
            } else {
                if (kq < 128){ src = Wih0; kloc = kq; rowlen = 128; }
                else         { src = Whh0; kloc = kq - 128; rowlen = 512; }
            }
#pragma unroll
            for (int gg = 0; gg < 3; ++gg){
                long row = (long)gg * Hh + c0 + n;
                make_wfrag(src + row * rowlen + kloc, whi[ks][gg], wlo[ks][gg]);
            }
        }
    }
    // ---- biases for epilogue ----
    float Br = 0.f, Bz = 0.f, Bin = 0.f, Bhn = 0.f;
    if (tid < 256){
        int c = c0 + (tid & 15);
        const float* bi = isL1 ? bih1 : bih0;
        const float* bh = isL1 ? bhh1 : bhh0;
        Br  = bi[c] + bh[c];
        Bz  = bi[Hh + c] + bh[Hh + c];
        Bin = bi[2*Hh + c];
        Bhn = bh[2*Hh + c];
    }

    for (int t = 0; t < Tt; ++t){
        // ---- staging: speculative plain x4 loads + ladder fix-up ----
        if (isL1){
            const unsigned* s0 = hseq0 + ((long)t * Bb + m*16) * (long)Hh;
            long r1 = BIG ? (long)(t-1) * BH : (long)((t-1) & 1) * BH;
            const unsigned* s1 = hseq1 + r1 + (long)(m*16) * Hh;
            unsigned tag1 = BIG ? 1u : (1u - (((unsigned)(t-1) >> 1) & 1u));
            const unsigned* a0[4]; const unsigned* a1[4];
            i32x4 v0[4], v1[4];
#pragma unroll
            for (int it = 0; it < 4; ++it){
                int j = it*512 + tid; int row = j >> 7, col = (j & 127) * 4;
                a0[it] = s0 + (long)row * Hh + col;
                v0[it] = *(const i32x4*)a0[it];
            }
            if (t > 0){
#pragma unroll
                for (int it = 0; it < 4; ++it){
                    int j = it*512 + tid; int row = j >> 7, col = (j & 127) * 4;
                    a1[it] = s1 + (long)row * Hh + col;
                    v1[it] = *(const i32x4*)a1[it];
                }
            }
#pragma unroll
            for (int it = 0; it < 4; ++it) fix4(a0[it], 1u, v0[it]);
            if (t > 0){
#pragma unroll
                for (int it = 0; it < 4; ++it) fix4(a1[it], tag1, v1[it]);
            } else {
#pragma unroll
                for (int it = 0; it < 4; ++it) v1[it] = i32x4{0,0,0,0};
            }
#pragma unroll
            for (int it = 0; it < 4; ++it){
                int j = it*512 + tid; int row = j >> 7, col = (j & 127) * 4;
                *(i32x4*)(Alds + row * S1 + col) = v0[it];
                *(i32x4*)(Alds + row * S1 + 512 + col) = v1[it];
            }
        } else {
            // X[t] fp32 (cached input) -> pack on the fly
            {
                int row = tid >> 5, c4 = (tid & 31) * 4;
                f32x4 xv = *(const f32x4*)(X + ((long)(m*16 + row) * Tt + t) * DIN + c4);
                i32x4 pv;
                pv[0] = (int)pack_split(xv[0]);
                pv[1] = (int)pack_split(xv[1]);
                pv[2] = (int)pack_split(xv[2]);
                pv[3] = (int)pack_split(xv[3]);
                *(i32x4*)(Alds + row * S0 + c4) = pv;
            }
            if (t > 0){
                const unsigned* s0 = hseq0 + ((long)(t-1) * Bb + m*16) * (long)Hh;
                const unsigned* a0[4]; i32x4 v0[4];
#pragma unroll
                for (int it = 0; it < 4; ++it){
                    int j = it*512 + tid; int row = j >> 7, col = (j & 127) * 4;
                    a0[it] = s0 + (long)row * Hh + col;
                    v0[it] = *(const i32x4*)a0[it];
                }
#pragma unroll
                for (int it = 0; it < 4; ++it) fix4(a0[it], 1u, v0[it]);
#pragma unroll
                for (int it = 0; it < 4; ++it){
                    int j = it*512 + tid; int row = j >> 7, col = (j & 127) * 4;
                    *(i32x4*)(Alds + row * S0 + 128 + col) = v0[it];
                }
            } else {
#pragma unroll
                for (int it = 0; it < 8; ++it){
                    int j = it*512 + tid;
                    *(u64*)(Alds + (j >> 8) * S0 + 128 + (j & 255) * 2) = 0ULL;
                }
            }
        }
        __syncthreads();

        // ---- MFMA: this wave's K-slice, tiles {r, z, nx-or-nh} ----
        if (active){
            f32x4 a0 = {0.f,0.f,0.f,0.f}, a1 = a0, a2 = a0;
            const unsigned* arow = Alds + (lane & 15) * STR + w * 128 + (lane >> 4) * 8;
#pragma unroll
            for (int ks = 0; ks < 4; ++ks){
                unsigned uu[8];
                *(i32x4*)&uu[0] = *(const i32x4*)(arow + ks*32);
                *(i32x4*)&uu[4] = *(const i32x4*)(arow + ks*32 + 4);
                bf16x8 ah, al; make_afrag(uu, ah, al);
                a0 = MFMA16(ah, whi[ks][0], a0, 0,0,0);
                a0 = MFMA16(ah, wlo[ks][0], a0, 0,0,0);
                a0 = MFMA16(al, whi[ks][0], a0, 0,0,0);
                a1 = MFMA16(ah, whi[ks][1], a1, 0,0,0);
                a1 = MFMA16(ah, wlo[ks][1], a1, 0,0,0);
                a1 = MFMA16(al, whi[ks][1], a1, 0,0,0);
                a2 = MFMA16(ah, whi[ks][2], a2, 0,0,0);
                a2 = MFMA16(ah, wlo[ks][2], a2, 0,0,0);
                a2 = MFMA16(al, whi[ks][2], a2, 0,0,0);
            }
            int q = lane >> 4, n = lane & 15;
#pragma unroll
            for (int r4 = 0; r4 < 4; ++r4){
                int idx = (q*4 + r4)*PR + n;
                P[w][0][idx] = a0[r4];
                P[w][1][idx] = a1[r4];
                P[w][2][idx] = a2[r4];
            }
        }
        __syncthreads();

        // ---- reduce partials + gates -> dual store (plain + agent) ----
        unsigned wtag = isL1 ? (BIG ? 1u : (1u - (((unsigned)t >> 1) & 1u))) : 1u;
        if (tid < 256){
            int bm = tid >> 4, n = tid & 15;
            int idx = bm * PR + n;
            float sr, sz, snx, snh;
            if (isL1){
                sr  = P[0][0][idx]+P[1][0][idx]+P[2][0][idx]+P[3][0][idx]
                    + P[4][0][idx]+P[5][0][idx]+P[6][0][idx]+P[7][0][idx];
                sz  = P[0][1][idx]+P[1][1][idx]+P[2][1][idx]+P[3][1][idx]
                    + P[4][1][idx]+P[5][1][idx]+P[6][1][idx]+P[7][1][idx];
                snx = P[0][2][idx]+P[1][2][idx]+P[2][2][idx]+P[3][2][idx];
                snh = P[4][2][idx]+P[5][2][idx]+P[6][2][idx]+P[7][2][idx];
            } else {
                sr  = P[0][0][idx]+P[1][0][idx]+P[2][0][idx]+P[3][0][idx]+P[4][0][idx];
                sz  = P[0][1][idx]+P[1][1][idx]+P[2][1][idx]+P[3][1][idx]+P[4][1][idx];
                snx = P[0][2][idx];
                snh = P[1][2][idx]+P[2][2][idx]+P[3][2][idx]+P[4][2][idx];
            }
            float r  = 1.f/(1.f + __expf(-(sr + Br)));
            float z  = 1.f/(1.f + __expf(-(sz + Bz)));
            float ee = __expf(2.f*(snx + Bin + r*(snh + Bhn)));
            float nn = 1.f - 2.f/(ee + 1.f);
            float hp = unpack_f32(Alds[bm*STR + HOFF + c0 + n]);
            float hnew = (1.f - z)*nn + z*hp;
            unsigned pk = (pack_split(hnew) & ~1u) | wtag;
            unsigned* dst = isL1
                ? hseq1 + (BIG ? (long)t * BH : (long)(t & 1) * BH)
                        + (long)(m*16 + bm) * Hh + c0 + n
                : hseq0 + ((long)t * Bb + m*16 + bm) * (long)Hh + c0 + n;
            st_plain(dst, pk);     // local XCD L2 (updates line in place)
            ast32(dst, pk);        // IF/MALL copy (cross-XCD + fallback)
        }
        __syncthreads();           // protect Alds before t+1 staging
    }

    // ---- FC epilogue: one layer1 block per m (same XCD as its group) ----
    if (isL1 && cb == 31){
        unsigned ftag = BIG ? 1u : (1u - (((unsigned)(Tt-1) >> 1) & 1u));
        const unsigned* hb = hseq1 + (BIG ? (long)(Tt-1) * BH : (long)((Tt-1) & 1) * BH);
        int half = lane >> 5, l5 = lane & 31;
        int b = m*16 + w*2 + half;
        const unsigned* hrow = hb + (long)b * Hh;
        float p = 0.f;
#pragma unroll
        for (int cch = 0; cch < 4; ++cch){
            int col = (l5 + 32*cch) * 4;
            i32x4 v = *(const i32x4*)(hrow + col);
            fix4(hrow + col, ftag, v);
#pragma unroll
            for (int jj = 0; jj < 4; ++jj)
                p += unpack_f32((unsigned)v[jj]) * fcW[col + jj];
        }
#pragma unroll
        for (int off = 16; off > 0; off >>= 1) p += __shfl_xor(p, off);
        if (l5 == 0) out[b] = p + fcb[0];
    }
}

extern "C" void kernel_launch(void* const* d_in, const int* in_sizes, int n_in,
                              void* d_out, int out_size, void* d_ws, size_t ws_size,
                              hipStream_t stream) {
    const float* X    = (const float*)d_in[0];
    const float* Wih0 = (const float*)d_in[1];
    const float* Whh0 = (const float*)d_in[2];
    const float* bih0 = (const float*)d_in[3];
    const float* bhh0 = (const float*)d_in[4];
    const float* Wih1 = (const float*)d_in[5];
    const float* Whh1 = (const float*)d_in[6];
    const float* bih1 = (const float*)d_in[7];
    const float* bhh1 = (const float*)d_in[8];
    const float* fcW  = (const float*)d_in[9];
    const float* fcb  = (const float*)d_in[10];
    float* out = (float*)d_out;

    // ws: hseq0 64 MiB | hseq1 64 MiB (BIG) or 256 KiB ring. No memset needed:
    // harness poisons ws to 0xAA (bit0=0 = invalid) before every launch.
    unsigned* hseq0 = (unsigned*)d_ws;
    unsigned* hseq1 = hseq0 + (long)Tt * BH;
    size_t need_big = (size_t)2 * Tt * BH * 4;    // 128 MiB
    bool big = ws_size >= need_big;

    if (big)
        gru_main<true><<<256, 512, 0, stream>>>(X, Wih0, Whh0, bih0, bhh0,
                                                Wih1, Whh1, bih1, bhh1, fcW, fcb,
                                                out, hseq0, hseq1);
    else
        gru_main<false><<<256, 512, 0, stream>>>(X, Wih0, Whh0, bih0, bhh0,
                                                 Wih1, Whh1, bih1, bhh1, fcW, fcb,
                                                 out, hseq0, hseq1);
}

// Round 8
// 2189.285 us; speedup vs baseline: 1.0621x; 1.0621x over previous
//
#include <hip/hip_runtime.h>

// GRU B=64, T=512, IN=128, H=512, L=2, OUT=1 (fp32 in/out).
// R8: wave-decoupled staging + 16B IF exchange + 1 barrier/step.
//   - Each wave owns a 128-col K-slice of A (LDS slice-private): it polls and
//     stages ONLY its own producers' data, then runs its MFMAs. No staging
//     barrier; slow/fast producers overlap.
//   - Exchange: producers store h as packed split-bf16 u32 with bit0 validity
//     tag via global_store_dwordx4 sc0 sc1 (coherence point). Recurrent
//     consumers load via global_load_dwordx4 sc0 sc1 rounds (bypass L1+L2 —
//     cannot see stale cached lines; per-dword tags make 16B tearing safe).
//     Cross-layer hseq0 (L0 runs ahead) tries a plain cached load first
//     (XCD L2 broadcast), falling back to IF rounds.
//   - 1 barrier/step: P partials parity-double-buffered; h_prev kept in a
//     register by its epilogue thread; store quads gathered by shuffle.
//   grid = 256 x 512 (1 block/CU). g=blockIdx&7: g<4 -> layer0 (m=g), else
//   layer1 (m=g-4); cb=blockIdx>>3 -> 16-col block. Entry agent-acquire
//   fence kills cross-replay stale cache lines (ws re-poisoned 0xAA).

constexpr int Bb = 64, Tt = 512, DIN = 128, Hh = 512;
constexpr int BH = Bb * Hh;
constexpr int S0 = 644;    // LDS A-row stride (u32), layer0
constexpr int S1 = 1028;   // layer1
constexpr int PR = 17;     // partials row stride

typedef float  f32x4  __attribute__((ext_vector_type(4)));
typedef short  bf16x8 __attribute__((ext_vector_type(8)));
typedef int    i32x4  __attribute__((ext_vector_type(4)));
typedef unsigned long long u64;

#define MFMA16 __builtin_amdgcn_mfma_f32_16x16x32_bf16

__device__ __forceinline__ unsigned rne_bf16(unsigned xb){
    return (xb + 0x7FFFu + ((xb >> 16) & 1u)) >> 16;
}
__device__ __forceinline__ unsigned pack_split(float x){
    unsigned hb = rne_bf16(__float_as_uint(x));
    float hf = __uint_as_float(hb << 16);
    unsigned lb = rne_bf16(__float_as_uint(x - hf));
    return (hb << 16) | lb;
}
__device__ __forceinline__ float unpack_f32(unsigned u){
    return __uint_as_float(u & 0xFFFF0000u) + __uint_as_float(u << 16);
}

union FragU { unsigned w[4]; bf16x8 v; };

__device__ __forceinline__ void make_wfrag(const float* p, bf16x8& wh, bf16x8& wl){
    FragU hi, lo;
#pragma unroll
    for (int i = 0; i < 4; ++i){
        unsigned pa = pack_split(p[2*i]), pb = pack_split(p[2*i+1]);
        hi.w[i] = (pa >> 16) | (pb & 0xFFFF0000u);
        lo.w[i] = (pa & 0xFFFFu) | (pb << 16);
    }
    wh = hi.v; wl = lo.v;
}
__device__ __forceinline__ void make_afrag(const unsigned* u, bf16x8& ah, bf16x8& al){
    FragU hi, lo;
#pragma unroll
    for (int i = 0; i < 4; ++i){
        unsigned a = u[2*i], b = u[2*i+1];
        hi.w[i] = (a >> 16) | (b & 0xFFFF0000u);
        lo.w[i] = (a & 0xFFFFu) | (b << 16);
    }
    ah = hi.v; al = lo.v;
}

// ---- IF-path (coherence point) 16B ops ----
__device__ __forceinline__ void st16_if(unsigned* p, i32x4 v){
    asm volatile("global_store_dwordx4 %0, %1, off sc0 sc1"
                 :: "v"(p), "v"(v) : "memory");
}
__device__ __forceinline__ unsigned tagbad(const i32x4& v, unsigned tag){
    return (((unsigned)v[0]^tag)|((unsigned)v[1]^tag)
           |((unsigned)v[2]^tag)|((unsigned)v[3]^tag)) & 1u;
}
// spin rounds of 8 IF x4-loads until all 32 dwords carry `tag` in bit0
__device__ __forceinline__ void ifld8(const unsigned* src, int cx, int r0,
                                      unsigned tag, i32x4 v[8]){
    for (;;){
#pragma unroll
        for (int i = 0; i < 8; ++i){
            const unsigned* a = src + (long)(2*i + r0) * Hh + cx;
            asm volatile("global_load_dwordx4 %0, %1, off sc0 sc1"
                         : "=v"(v[i]) : "v"(a));
        }
        asm volatile("s_waitcnt vmcnt(0)" ::: "memory");
        unsigned x = 0;
#pragma unroll
        for (int i = 0; i < 8; ++i) x |= tagbad(v[i], tag);
        if (!__any(x != 0u)) return;
        __builtin_amdgcn_s_sleep(1);
    }
}
// speculative cached attempt; true if all tags valid
__device__ __forceinline__ bool spec8(const unsigned* src, int cx, int r0,
                                      unsigned tag, i32x4 v[8]){
#pragma unroll
    for (int i = 0; i < 8; ++i)
        v[i] = *(const i32x4*)(src + (long)(2*i + r0) * Hh + cx);
    unsigned x = 0;
#pragma unroll
    for (int i = 0; i < 8; ++i) x |= tagbad(v[i], tag);
    return !__any(x != 0u);
}
__device__ __forceinline__ void wr8(unsigned* ldsb, int STRv, int cx, int r0,
                                    const i32x4 v[8]){
#pragma unroll
    for (int i = 0; i < 8; ++i)
        *(i32x4*)(ldsb + (2*i + r0) * STRv + cx) = v[i];
}

template<bool BIG>
__global__ __launch_bounds__(512, 1) void gru_main(
    const float* __restrict__ X,
    const float* __restrict__ Wih0, const float* __restrict__ Whh0,
    const float* __restrict__ bih0, const float* __restrict__ bhh0,
    const float* __restrict__ Wih1, const float* __restrict__ Whh1,
    const float* __restrict__ bih1, const float* __restrict__ bhh1,
    const float* __restrict__ fcW, const float* __restrict__ fcb,
    float* __restrict__ out,
    unsigned* hseq0, unsigned* hseq1)
{
    // Kill stale cached lines from the previous graph replay (one buffer_inv).
    __builtin_amdgcn_fence(__ATOMIC_ACQUIRE, "agent");

    __shared__ unsigned Alds[16 * S1];
    __shared__ float P[2][8][3][16 * PR];     // parity double-buffered partials

    const int tid  = threadIdx.x;
    const int lane = tid & 63;
    const int w    = tid >> 6;
    const int g    = (int)blockIdx.x & 7;      // XCD class under round-robin
    const bool isL1 = g >= 4;
    const int m  = g & 3;                      // batch tile 0..3
    const int cb = (int)blockIdx.x >> 3;       // col-block 0..31
    const int c0 = cb * 16;
    const int STR = isL1 ? S1 : S0;
    const int cx  = (lane & 31) * 4;           // staging x4 column
    const int r0  = lane >> 5;                 // staging row parity

    const bool active = isL1 || (w < 5);       // layer0 K=640 -> 5 waves

    // ---- register-resident weight fragments (hi/lo split-bf16) ----
    bf16x8 whi[4][3], wlo[4][3];
    if (active){
        const int n = lane & 15;
#pragma unroll
        for (int ks = 0; ks < 4; ++ks){
            int kq = w * 128 + ks * 32 + (lane >> 4) * 8;
            const float* src; long kloc, rowlen;
            if (isL1){
                if (kq < 512){ src = Wih1; kloc = kq; } else { src = Whh1; kloc = kq - 512; }
                rowlen = 512;
            } else {
                if (kq < 128){ src = Wih0; kloc = kq; rowlen = 128; }
                else         { src = Whh0; kloc = kq - 128; rowlen = 512; }
            }
#pragma unroll
            for (int gg = 0; gg < 3; ++gg){
                long row = (long)gg * Hh + c0 + n;
                make_wfrag(src + row * rowlen + kloc, whi[ks][gg], wlo[ks][gg]);
            }
        }
    }
    // ---- biases + register h_prev for epilogue threads ----
    float Br = 0.f, Bz = 0.f, Bin = 0.f, Bhn = 0.f, hp = 0.f;
    if (tid < 256){
        int c = c0 + (tid & 15);
        const float* bi = isL1 ? bih1 : bih0;
        const float* bh = isL1 ? bhh1 : bhh0;
        Br  = bi[c] + bh[c];
        Bz  = bi[Hh + c] + bh[Hh + c];
        Bin = bi[2*Hh + c];
        Bhn = bh[2*Hh + c];
    }

    for (int t = 0; t < Tt; ++t){
        // ---- per-wave staging of this wave's K-slice (no barrier) ----
        i32x4 sv[8];
        if (isL1){
            if (w < 4){
                // cross-layer h0[t]: L0 runs ahead -> cached spec, IF fallback
                const unsigned* src = hseq0 + ((long)t * Bb + m*16) * (long)Hh + w*128;
                if (!spec8(src, cx, r0, 1u, sv)) ifld8(src, cx, r0, 1u, sv);
            } else {
                if (t > 0){
                    long r1 = BIG ? (long)(t-1) * BH : (long)((t-1) & 1) * BH;
                    unsigned tag1 = BIG ? 1u : (1u - (((unsigned)(t-1) >> 1) & 1u));
                    const unsigned* src = hseq1 + r1 + (long)(m*16) * Hh + (w-4)*128;
                    ifld8(src, cx, r0, tag1, sv);
                } else {
#pragma unroll
                    for (int i = 0; i < 8; ++i) sv[i] = i32x4{0,0,0,0};
                }
            }
            wr8(Alds + w*128, S1, cx, r0, sv);
        } else {
            if (w == 0){
                // X[t] fp32 -> pack on the fly (pure input, never waits)
#pragma unroll
                for (int i = 0; i < 8; ++i){
                    int row = 2*i + r0;
                    f32x4 xv = *(const f32x4*)(X + ((long)(m*16 + row) * Tt + t) * DIN + cx);
                    sv[i][0] = (int)pack_split(xv[0]);
                    sv[i][1] = (int)pack_split(xv[1]);
                    sv[i][2] = (int)pack_split(xv[2]);
                    sv[i][3] = (int)pack_split(xv[3]);
                }
                wr8(Alds, S0, cx, r0, sv);
            } else if (w < 5){
                if (t > 0){
                    const unsigned* src = hseq0 + ((long)(t-1) * Bb + m*16) * (long)Hh
                                        + (w-1)*128;
                    ifld8(src, cx, r0, 1u, sv);
                } else {
#pragma unroll
                    for (int i = 0; i < 8; ++i) sv[i] = i32x4{0,0,0,0};
                }
                wr8(Alds + w*128, S0, cx, r0, sv);
            }
        }

        // ---- MFMA on own slice -> parity P ----
        if (active){
            f32x4 a0 = {0.f,0.f,0.f,0.f}, a1 = a0, a2 = a0;
            const unsigned* arow = Alds + (lane & 15) * STR + w * 128 + (lane >> 4) * 8;
#pragma unroll
            for (int ks = 0; ks < 4; ++ks){
                unsigned uu[8];
                *(i32x4*)&uu[0] = *(const i32x4*)(arow + ks*32);
                *(i32x4*)&uu[4] = *(const i32x4*)(arow + ks*32 + 4);
                bf16x8 ah, al; make_afrag(uu, ah, al);
                a0 = MFMA16(ah, whi[ks][0], a0, 0,0,0);
                a0 = MFMA16(ah, wlo[ks][0], a0, 0,0,0);
                a0 = MFMA16(al, whi[ks][0], a0, 0,0,0);
                a1 = MFMA16(ah, whi[ks][1], a1, 0,0,0);
                a1 = MFMA16(ah, wlo[ks][1], a1, 0,0,0);
                a1 = MFMA16(al, whi[ks][1], a1, 0,0,0);
                a2 = MFMA16(ah, whi[ks][2], a2, 0,0,0);
                a2 = MFMA16(ah, wlo[ks][2], a2, 0,0,0);
                a2 = MFMA16(al, whi[ks][2], a2, 0,0,0);
            }
            int q = lane >> 4, n = lane & 15;
            float (*Pp)[16*PR] = P[t & 1][w];
#pragma unroll
            for (int r4 = 0; r4 < 4; ++r4){
                int idx = (q*4 + r4)*PR + n;
                Pp[0][idx] = a0[r4];
                Pp[1][idx] = a1[r4];
                Pp[2][idx] = a2[r4];
            }
        }
        __syncthreads();   // the ONLY barrier per step

        // ---- epilogue (waves 0-3): reduce parity P, gates, tagged IF store ----
        if (tid < 256){
            int bm = tid >> 4, n = tid & 15;
            int idx = bm * PR + n;
            float (*Pw)[3][16*PR] = P[t & 1];
            float sr, sz, snx, snh;
            if (isL1){
                sr  = Pw[0][0][idx]+Pw[1][0][idx]+Pw[2][0][idx]+Pw[3][0][idx]
                    + Pw[4][0][idx]+Pw[5][0][idx]+Pw[6][0][idx]+Pw[7][0][idx];
                sz  = Pw[0][1][idx]+Pw[1][1][idx]+Pw[2][1][idx]+Pw[3][1][idx]
                    + Pw[4][1][idx]+Pw[5][1][idx]+Pw[6][1][idx]+Pw[7][1][idx];
                snx = Pw[0][2][idx]+Pw[1][2][idx]+Pw[2][2][idx]+Pw[3][2][idx];
                snh = Pw[4][2][idx]+Pw[5][2][idx]+Pw[6][2][idx]+Pw[7][2][idx];
            } else {
                sr  = Pw[0][0][idx]+Pw[1][0][idx]+Pw[2][0][idx]+Pw[3][0][idx]+Pw[4][0][idx];
                sz  = Pw[0][1][idx]+Pw[1][1][idx]+Pw[2][1][idx]+Pw[3][1][idx]+Pw[4][1][idx];
                snx = Pw[0][2][idx];
                snh = Pw[1][2][idx]+Pw[2][2][idx]+Pw[3][2][idx]+Pw[4][2][idx];
            }
            float r  = 1.f/(1.f + __expf(-(sr + Br)));
            float z  = 1.f/(1.f + __expf(-(sz + Bz)));
            float ee = __expf(2.f*(snx + Bin + r*(snh + Bhn)));
            float nn = 1.f - 2.f/(ee + 1.f);
            float hnew = (1.f - z)*nn + z*hp;
            hp = hnew;                                   // register h_prev
            unsigned wtag = isL1 ? (BIG ? 1u : (1u - (((unsigned)t >> 1) & 1u))) : 1u;
            unsigned pk = (pack_split(hnew) & ~1u) | wtag;
            // gather the x4 quad by shuffle, store by n%4==0 lanes
            int qb = lane & ~3;
            unsigned p0 = __shfl(pk, qb + 0);
            unsigned p1 = __shfl(pk, qb + 1);
            unsigned p2 = __shfl(pk, qb + 2);
            unsigned p3 = __shfl(pk, qb + 3);
            if ((n & 3) == 0){
                unsigned* dstb = isL1
                    ? hseq1 + (BIG ? (long)t * BH : (long)(t & 1) * BH)
                    : hseq0 + (long)t * BH;
                i32x4 pv; pv[0]=(int)p0; pv[1]=(int)p1; pv[2]=(int)p2; pv[3]=(int)p3;
                st16_if(dstb + (long)(m*16 + bm) * Hh + c0 + n, pv);
            }
        }
    }

    // ---- FC epilogue: one layer1 block per m, validated IF reads ----
    if (isL1 && cb == 31){
        unsigned ftag = BIG ? 1u : (1u - (((unsigned)(Tt-1) >> 1) & 1u));
        const unsigned* hb = hseq1 + (BIG ? (long)(Tt-1) * BH : (long)((Tt-1) & 1) * BH);
        int half = lane >> 5, l5 = lane & 31;
        int b = m*16 + w*2 + half;
        const unsigned* hrow = hb + (long)b * Hh;
        i32x4 vv[4];
        for (;;){
#pragma unroll
            for (int c = 0; c < 4; ++c){
                const unsigned* a = hrow + (l5 + 32*c) * 4;
                asm volatile("global_load_dwordx4 %0, %1, off sc0 sc1"
                             : "=v"(vv[c]) : "v"(a));
            }
            asm volatile("s_waitcnt vmcnt(0)" ::: "memory");
            unsigned x = 0;
#pragma unroll
            for (int c = 0; c < 4; ++c) x |= tagbad(vv[c], ftag);
            if (!__any(x != 0u)) break;
            __builtin_amdgcn_s_sleep(1);
        }
        float p = 0.f;
#pragma unroll
        for (int c = 0; c < 4; ++c){
            int col = (l5 + 32*c) * 4;
#pragma unroll
            for (int jj = 0; jj < 4; ++jj)
                p += unpack_f32((unsigned)vv[c][jj]) * fcW[col + jj];
        }
#pragma unroll
        for (int off = 16; off > 0; off >>= 1) p += __shfl_xor(p, off);
        if (l5 == 0) out[b] = p + fcb[0];
    }
}

extern "C" void kernel_launch(void* const* d_in, const int* in_sizes, int n_in,
                              void* d_out, int out_size, void* d_ws, size_t ws_size,
                              hipStream_t stream) {
    const float* X    = (const float*)d_in[0];
    const float* Wih0 = (const float*)d_in[1];
    const float* Whh0 = (const float*)d_in[2];
    const float* bih0 = (const float*)d_in[3];
    const float* bhh0 = (const float*)d_in[4];
    const float* Wih1 = (const float*)d_in[5];
    const float* Whh1 = (const float*)d_in[6];
    const float* bih1 = (const float*)d_in[7];
    const float* bhh1 = (const float*)d_in[8];
    const float* fcW  = (const float*)d_in[9];
    const float* fcb  = (const float*)d_in[10];
    float* out = (float*)d_out;

    // ws: hseq0 64 MiB | hseq1 64 MiB (BIG) or 256 KiB ring. No memset:
    // harness poisons ws to 0xAA (bit0=0 = invalid) before every launch.
    unsigned* hseq0 = (unsigned*)d_ws;
    unsigned* hseq1 = hseq0 + (long)Tt * BH;
    size_t need_big = (size_t)2 * Tt * BH * 4;    // 128 MiB
    bool big = ws_size >= need_big;

    if (big)
        gru_main<true><<<256, 512, 0, stream>>>(X, Wih0, Whh0, bih0, bhh0,
                                                Wih1, Whh1, bih1, bhh1, fcW, fcb,
                                                out, hseq0, hseq1);
    else
        gru_main<false><<<256, 512, 0, stream>>>(X, Wih0, Whh0, bih0, bhh0,
                                                 Wih1, Whh1, bih1, bhh1, fcW, fcb,
                                                 out, hseq0, hseq1);
}